// Round 7
// baseline (423.226 us; speedup 1.0000x reference)
//
#include <hip/hip_runtime.h>
#include <hip/hip_bf16.h>
#include <stdint.h>
#include <stddef.h>

// Problem constants
#define B_   2
#define L_   2048
#define E_   2048
#define H_   16
#define D_   128
#define F_   2048          // QKV_FEATURES
#define NROW (B_*L_)       // 4096
#define QS   6144          // fused qkv row stride (3*F_)

typedef __bf16 bf16_t;
typedef __bf16 bf16x4 __attribute__((ext_vector_type(4)));
typedef __bf16 bf16x8 __attribute__((ext_vector_type(8)));
typedef float  f32x4  __attribute__((ext_vector_type(4)));

// async global->LDS, 16B per lane. LDS dest = wave-uniform base + lane*16.
__device__ __forceinline__ void gload16(const void* g, void* l) {
  __builtin_amdgcn_global_load_lds(
      (const __attribute__((address_space(1))) void*)g,
      (__attribute__((address_space(3))) void*)l, 16, 0, 0);
}

#define VMC(n)  asm volatile("s_waitcnt vmcnt(" #n ")" ::: "memory")
#define BAR_MID do { asm volatile("" ::: "memory"); __builtin_amdgcn_s_barrier(); \
  asm volatile("s_waitcnt lgkmcnt(0)" ::: "memory"); __builtin_amdgcn_sched_barrier(0); } while(0)
#define BAR_END do { asm volatile("" ::: "memory"); __builtin_amdgcn_s_barrier(); } while(0)

// ---------------- fused prep: x->bf16 | 4x W transpose+convert | sincos table ----------------
__global__ __launch_bounds__(256) void k_prep(const float* __restrict__ x,
                                              const float* __restrict__ Wq,
                                              const float* __restrict__ Wk,
                                              const float* __restrict__ Wv,
                                              const float* __restrict__ Wo,
                                              bf16_t* __restrict__ xb,
                                              bf16_t* __restrict__ wqkvt,
                                              bf16_t* __restrict__ wot,
                                              float2* __restrict__ sc) {
  const int bb = blockIdx.x;
  if (bb < 8192) {                       // convert x (NROW*E_/4 = 2M float4 groups)
    int i = bb*256 + threadIdx.x;
    float4 v = ((const float4*)x)[i];
    bf16x4 t;
    t[0] = (__bf16)v.x; t[1] = (__bf16)v.y; t[2] = (__bf16)v.z; t[3] = (__bf16)v.w;
    ((bf16x4*)xb)[i] = t;
  } else if (bb < 24576) {               // weight transposes (64x64 tiles x 4 mats)
    __shared__ float tile[32][33];
    const int r4 = bb - 8192;
    const int z  = r4 >> 12;
    const int xy = r4 & 4095;
    const int ct = xy & 63, rt = xy >> 6;
    const float* in = (z == 0) ? Wq : (z == 1) ? Wk : (z == 2) ? Wv : Wo;
    bf16_t* out = (z < 3) ? wqkvt + (size_t)z*F_*E_ : wot;
    const int c = threadIdx.x & 31, r0 = threadIdx.x >> 5;
    #pragma unroll
    for (int k = 0; k < 4; k++) {
      int r = r0 + k*8;
      tile[r][c] = in[(size_t)(rt*32 + r)*2048 + ct*32 + c];
    }
    __syncthreads();
    #pragma unroll
    for (int k = 0; k < 4; k++) {
      int r = r0 + k*8;
      out[(size_t)(ct*32 + r)*2048 + rt*32 + c] = (__bf16)tile[c][r];
    }
  } else {                               // sincos table (L_*64 entries)
    int id = (bb - 24576)*256 + threadIdx.x;
    int t = id >> 6, i = id & 63;
    float freq = powf(10000.0f, -(float)i / 64.0f);
    float a = (float)t * freq;
    sc[id] = make_float2(cosf(a), sinf(a));
  }
}

// -------- transpose V: qkv v-slice [B*L][QS] bf16 -> Vt [B][H][D][L] bf16 --------
__global__ __launch_bounds__(256) void k_vt(const bf16_t* __restrict__ qkv,
                                            bf16_t* __restrict__ vt) {
  __shared__ bf16_t tile[32][33];
  const int bb = blockIdx.x;
  const int lt = bb & 63, dt = (bb >> 6) & 3, bh = bb >> 8;
  const int b = bh >> 4, h = bh & 15;
  const int c = threadIdx.x & 31, r0 = threadIdx.x >> 5;
  #pragma unroll
  for (int k = 0; k < 4; k++) {
    int r = r0 + k*8;
    tile[r][c] = qkv[(size_t)(b*L_ + lt*32 + r)*QS + 2*F_ + h*D_ + dt*32 + c];
  }
  __syncthreads();
  #pragma unroll
  for (int k = 0; k < 4; k++) {
    int r = r0 + k*8;
    vt[(size_t)(bh*D_ + dt*32 + r)*L_ + lt*32 + c] = tile[c][r];
  }
}

// ======== GEMM: BM=128 x BN=256, BK=64, 3-deep LDS pipeline, 2 phases/K-tile ========
// C[M][N] = A[M][K] x BT[N][K], bf16, fp32 accum. 512 thr (8 waves, 2M x 4N; per-wave 64x64).
// LDS 144KB: A-buf i (16KB) at i*16384; B-buf i (32KB) at 49152+i*32768. Tile u -> buf u%3.
// Ledger: at group-u entry the vmem queue is EXACTLY tile u+1's 6 loads (inductive);
// group u issues tile u+2's 6 loads (ph1: A+B01, ph2: B23) into buf (u+2)%3 (WAR-safe,
// distinct from bufs u%3 and (u+1)%3); VMC(6) at end of ph2 drains tile u+1 (>=2-group
// flight for every load; never vmcnt(0) until the last two groups).
// MODE 1: bf16 out + fused RoPE on q/k thirds (pair = adjacent lanes via shfl_xor 1).
// MODE 2: f32 out + bias.
// Column-band XCD map: XCD x owns bx in [x*band, (x+1)*band) -> B panels stay L2-hot.
#define RDA(BASE) do { _Pragma("unroll") for (int m_=0;m_<4;m_++) { \
  a[m_][0] = *(const bf16x8*)((BASE) + m_*2048 + cs0); \
  a[m_][1] = *(const bf16x8*)((BASE) + m_*2048 + cs1); } } while(0)
#define RDB(BASE, NB) do { _Pragma("unroll") for (int n_=0;n_<2;n_++) { \
  bb_[n_][0] = *(const bf16x8*)((BASE) + ((NB)+n_)*2048 + cs0); \
  bb_[n_][1] = *(const bf16x8*)((BASE) + ((NB)+n_)*2048 + cs1); } } while(0)
#define MMQ(NB) do { __builtin_amdgcn_s_setprio(1); \
  _Pragma("unroll") for (int m_=0;m_<4;m_++) { \
    _Pragma("unroll") for (int n_=0;n_<2;n_++) { \
      acc[m_][(NB)+n_] = __builtin_amdgcn_mfma_f32_16x16x32_bf16(a[m_][0], bb_[n_][0], acc[m_][(NB)+n_], 0, 0, 0); \
      acc[m_][(NB)+n_] = __builtin_amdgcn_mfma_f32_16x16x32_bf16(a[m_][1], bb_[n_][1], acc[m_][(NB)+n_], 0, 0, 0); } } \
  __builtin_amdgcn_s_setprio(0); } while(0)

template<typename OutT, int MODE>
__global__ __launch_bounds__(512, 1) void k_gemm256(const bf16_t* __restrict__ A,
                                                    const bf16_t* __restrict__ BT,
                                                    OutT* __restrict__ C,
                                                    const float* __restrict__ bias,
                                                    const float2* __restrict__ sc,
                                                    float qscale,
                                                    int M, int N, int K) {
  __shared__ char sm[147456];
  const int tid = threadIdx.x, lane = tid & 63, wave = tid >> 6;
  const int wr = wave >> 2, wc = wave & 3;       // 2M x 4N
  const int lr = lane & 15, lg = lane >> 4;
  const int nbx = N >> 8;                        // 256-col tiles
  const int band = nbx >> 3;                     // nbx % 8 == 0
  const int bid = blockIdx.x;
  const int idx = bid >> 3;
  const int bx = (bid & 7)*band + idx % band;
  const int by = idx / band;
  const int row0 = by << 7, col0 = bx << 8;
  // staging source (pre-swizzled 16B chunk so linear LDS dest lands swizzled)
  const int sr  = tid >> 3;                      // 0..63
  const int sxe = ((tid & 7) ^ (sr & 7)) << 3;
  const bf16_t* Ag = A  + (size_t)(row0 + sr)*K + sxe;
  const bf16_t* Bg = BT + (size_t)(col0 + sr)*K + sxe;
  auto stA = [&](int t) {                        // A tile: 128 rows, 2 gloads
    const bf16_t* s = Ag + t*64;
    char* d = sm + (t % 3)*16384 + wave*1024;
    gload16(s, d); gload16(s + (size_t)64*K, d + 8192);
  };
  auto stB01 = [&](int t) {                      // B rows 0..127
    const bf16_t* s = Bg + t*64;
    char* d = sm + 49152 + (t % 3)*32768 + wave*1024;
    gload16(s, d); gload16(s + (size_t)64*K, d + 8192);
  };
  auto stB23 = [&](int t) {                      // B rows 128..255
    const bf16_t* s = Bg + (size_t)128*K + t*64;
    char* d = sm + 49152 + (t % 3)*32768 + 16384 + wave*1024;
    gload16(s, d); gload16(s + (size_t)64*K, d + 8192);
  };
  // frag reads: row r at r*128 + ((ks*4+lg)^(r&7))*16; r&7 == lr&7
  const int cs0 = (lg ^ (lr & 7)) << 4;
  const int cs1 = ((4 + lg) ^ (lr & 7)) << 4;

  f32x4 acc[4][4] = {};
  bf16x8 a[4][2], bb_[2][2];

  // prologue: tiles 0 and 1 fully staged; drain tile 0, keep tile 1 in flight
  stA(0); stB01(0); stB23(0);
  stA(1); stB01(1); stB23(1);
  VMC(6);
  BAR_END;

  const int nt = K >> 6;
  for (int u = 0; u < nt; u++) {
    const int bi = u % 3;
    const char* Ab = sm + bi*16384 + (wr*64 + lr)*128;
    const char* Bb = sm + 49152 + bi*32768 + (wc*64 + lr)*128;
    // ph1: read A(all) + B(n0,n1); stage tile u+2's A and B-half0
    RDA(Ab);
    RDB(Bb, 0);
    if (u + 2 < nt) { stA(u+2); stB01(u+2); }
    BAR_MID;
    MMQ(0);
    BAR_END;
    // ph2: read B(n2,n3); stage tile u+2's B-half1; checkpoint drains tile u+1
    RDB(Bb, 2);
    if (u + 2 < nt) stB23(u+2);
    BAR_MID;
    MMQ(2);
    if (u + 2 < nt) { VMC(6); } else { VMC(0); }
    BAR_END;
  }
  // epilogue: C/D layout col=lane&15, row=(lane>>4)*4+j (m89-verified)
  #pragma unroll
  for (int m = 0; m < 4; m++) {
    #pragma unroll
    for (int n = 0; n < 4; n++) {
      const int col = col0 + wc*64 + n*16 + lr;
      if (MODE == 2) {
        const float bv = bias[col];
        #pragma unroll
        for (int j = 0; j < 4; j++) {
          const int row = row0 + wr*64 + m*16 + lg*4 + j;
          C[(size_t)row*N + col] = (OutT)(acc[m][n][j] + bv);
        }
      } else {
        // MODE 1: fused RoPE on q (third 0, pre-scaled) and k (third 1) in f32.
        const int third = col >> 11;
        const int ii    = (col & (D_-1)) >> 1;
        const bool odd  = (lr & 1);
        const float ss  = (third == 0) ? qscale : 1.0f;
        #pragma unroll
        for (int j = 0; j < 4; j++) {
          const int row = row0 + wr*64 + m*16 + lg*4 + j;
          const float v0 = acc[m][n][j];
          const float vp = __shfl_xor(v0, 1);
          float res;
          if (third == 2) {
            res = v0;
          } else {
            const int t = row & (L_-1);
            const float2 cs = sc[t*64 + ii];
            const float cosv = cs.x * ss, sinv = cs.y * ss;
            res = odd ? (vp*sinv + v0*cosv) : (v0*cosv - vp*sinv);
          }
          C[(size_t)row*N + col] = (OutT)res;
        }
      }
    }
  }
}

// -------- Flash attention tile compute (swapped-operand form) --------
template<bool MASK>
__device__ __forceinline__ void attn_tile(
    int kv0, int wq0, int lr, int lg,
    const char* __restrict__ Kb, const char* __restrict__ Vb, char* __restrict__ Pb,
    const bf16x8 (&aq)[4], f32x4 (&o)[8], float& mrow, float& lsum) {
  const int swz = (lr & 7) << 4;
  f32x4 s[4] = {};
  #pragma unroll
  for (int kd = 0; kd < 4; kd++) {
    bf16x8 ak[4];
    #pragma unroll
    for (int n = 0; n < 4; n++)
      ak[n] = *(const bf16x8*)(Kb + (n*16 + lr)*256 + (((kd*4 + lg) << 4) ^ swz));
    __builtin_amdgcn_s_setprio(1);
    #pragma unroll
    for (int n = 0; n < 4; n++)
      s[n] = __builtin_amdgcn_mfma_f32_16x16x32_bf16(ak[n], aq[kd], s[n], 0, 0, 0);
    __builtin_amdgcn_s_setprio(0);
  }
  if (MASK) {
    const int q = wq0 + lr;
    #pragma unroll
    for (int n = 0; n < 4; n++)
      #pragma unroll
      for (int j = 0; j < 4; j++)
        if (kv0 + n*16 + lg*4 + j > q) s[n][j] = -30000.0f;
  }
  float pmax = fmaxf(
      fmaxf(fmaxf(fmaxf(s[0][0], s[0][1]), fmaxf(s[0][2], s[0][3])),
            fmaxf(fmaxf(s[1][0], s[1][1]), fmaxf(s[1][2], s[1][3]))),
      fmaxf(fmaxf(fmaxf(s[2][0], s[2][1]), fmaxf(s[2][2], s[2][3])),
            fmaxf(fmaxf(s[3][0], s[3][1]), fmaxf(s[3][2], s[3][3]))));
  pmax = fmaxf(pmax, __shfl_xor(pmax, 16));
  pmax = fmaxf(pmax, __shfl_xor(pmax, 32));
  if (!__all(pmax - mrow <= 8.0f)) {       // defer-max (T13)
    const float mnew = fmaxf(mrow, pmax);
    const float corr = exp2f(mrow - mnew);
    mrow = mnew;
    lsum *= corr;
    #pragma unroll
    for (int n2 = 0; n2 < 8; n2++) o[n2] *= corr;
  }
  float rs = 0.0f;
  #pragma unroll
  for (int n = 0; n < 4; n++)
    #pragma unroll
    for (int j = 0; j < 4; j++) {
      float p = exp2f(s[n][j] - mrow);
      s[n][j] = p;
      rs += p;
    }
  rs += __shfl_xor(rs, 16);
  rs += __shfl_xor(rs, 32);
  lsum += rs;
  #pragma unroll
  for (int n = 0; n < 4; n++) {
    bf16x4 pw;
    pw[0] = (__bf16)s[n][0]; pw[1] = (__bf16)s[n][1];
    pw[2] = (__bf16)s[n][2]; pw[3] = (__bf16)s[n][3];
    *(bf16x4*)(Pb + ((lr*128 + n*32 + lg*8) ^ swz)) = pw;
  }
  #pragma unroll
  for (int ks = 0; ks < 2; ks++) {
    bf16x8 pb = *(const bf16x8*)(Pb + ((lr*128 + ks*64 + lg*16) ^ swz));
    __builtin_amdgcn_s_setprio(1);
    #pragma unroll
    for (int n2 = 0; n2 < 8; n2++) {
      bf16x8 av = *(const bf16x8*)(Vb + (n2*16 + lr)*128 + (((ks*4 + lg) << 4) ^ swz));
      o[n2] = __builtin_amdgcn_mfma_f32_16x16x32_bf16(av, pb, o[n2], 0, 0, 0);
    }
    __builtin_amdgcn_s_setprio(0);
  }
}

// -------- Flash attention, causal. 8 waves x 16 q-rows. Flat grid 512. --------
// XCD bh-chunking: XCD x owns 4 whole (b,h) pairs (K+V = 4MB, L2-fit),
// qt descending within chunk (heavy first).
__global__ __launch_bounds__(512, 4) void k_attn(const bf16_t* __restrict__ QKV,
                                                 const bf16_t* __restrict__ Vt,
                                                 bf16_t* __restrict__ O) {
  __shared__ bf16_t Ks[2][64*128];
  __shared__ bf16_t Vs[2][128*64];
  __shared__ bf16_t Pl[8][16*64];
  const int tid = threadIdx.x, lane = tid & 63, wave = tid >> 6;
  const int bidx = blockIdx.x;
  const int xcd = bidx & 7, idx = bidx >> 3;       // idx 0..63
  const int bh  = xcd*4 + (idx & 3);               // 4 (b,h) pairs per XCD
  const int qt  = 15 - (idx >> 2);                 // heavy first
  const int b = bh >> 4, h = bh & 15;
  const int wq0 = qt*128 + wave*16;
  const int lr = lane & 15, lg = lane >> 4;
  char* Pb = (char*)&Pl[wave][0];
  const bf16_t* Q = QKV;
  const bf16_t* K = QKV + F_;

  bf16x8 aq[4];
  #pragma unroll
  for (int kd = 0; kd < 4; kd++)
    aq[kd] = *(const bf16x8*)&Q[(size_t)(b*L_ + wq0 + lr)*QS + h*D_ + kd*32 + lg*8];

  const int kr = tid >> 4, kc = tid & 15;
  const bf16_t* Kg0 = K + (size_t)(b*L_ + kr)*QS + h*D_ + ((kc ^ (kr & 7)) << 3);
  const int vr = tid >> 3, vc = tid & 7;
  const bf16_t* Vg0 = Vt + (size_t)((b*H_ + h)*D_ + vr)*L_ + ((vc ^ (vr & 7)) << 3);

  f32x4 o[8] = {};
  float mrow = -3.0e38f, lsum = 0.0f;
  const int ntb   = 2*qt + 2;
  const int nfull = (wq0 + 1) >> 6;
  const int nmine = ((wq0 + 15) >> 6) + 1;

  {
    char* kb = (char*)&Ks[0][0] + wave*1024;
    char* vb = (char*)&Vs[0][0] + wave*1024;
    gload16(Kg0,                 kb);
    gload16(Kg0 + (size_t)32*QS, kb + 8192);
    gload16(Vg0,                 vb);
    gload16(Vg0 + (size_t)64*L_, vb + 8192);
  }
  __syncthreads();

  int buf = 0;
  for (int t = 0; t < ntb; t++) {
    if (t + 1 < ntb) {
      const int kn = (t+1)*64;
      char* kb = (char*)&Ks[buf^1][0] + wave*1024;
      char* vb = (char*)&Vs[buf^1][0] + wave*1024;
      const bf16_t* kg = Kg0 + (size_t)kn*QS;
      const bf16_t* vg = Vg0 + kn;
      gload16(kg,                 kb);
      gload16(kg + (size_t)32*QS, kb + 8192);
      gload16(vg,                 vb);
      gload16(vg + (size_t)64*L_, vb + 8192);
    }
    const char* Kb = (const char*)&Ks[buf][0];
    const char* Vb = (const char*)&Vs[buf][0];
    if (t < nfull)
      attn_tile<false>(t*64, wq0, lr, lg, Kb, Vb, Pb, aq, o, mrow, lsum);
    else if (t < nmine)
      attn_tile<true >(t*64, wq0, lr, lg, Kb, Vb, Pb, aq, o, mrow, lsum);
    __syncthreads();
    buf ^= 1;
  }
  const float inv = 1.0f / lsum;
  bf16_t* orow = O + (size_t)(b*L_ + wq0 + lr)*F_ + h*D_ + lg*4;
  #pragma unroll
  for (int n2 = 0; n2 < 8; n2++) {
    bf16x4 ov;
    ov[0] = (__bf16)(o[n2][0]*inv); ov[1] = (__bf16)(o[n2][1]*inv);
    ov[2] = (__bf16)(o[n2][2]*inv); ov[3] = (__bf16)(o[n2][3]*inv);
    *(bf16x4*)(orow + n2*16) = ov;
  }
}

extern "C" void kernel_launch(void* const* d_in, const int* in_sizes, int n_in,
                              void* d_out, int out_size, void* d_ws, size_t ws_size,
                              hipStream_t stream) {
  const float* x  = (const float*)d_in[0];
  const float* Wq = (const float*)d_in[1];
  const float* Wk = (const float*)d_in[2];
  const float* Wv = (const float*)d_in[3];
  const float* Wo = (const float*)d_in[4];
  const float* bo = (const float*)d_in[5];
  float* out = (float*)d_out;

  char* ws = (char*)d_ws;
  size_t off = 0;
  auto alloc = [&](size_t bytes) {
    char* p = ws + off;
    off = (off + bytes + 255) & ~(size_t)255;
    return p;
  };
  bf16_t* xb    = (bf16_t*)alloc((size_t)NROW*E_*2);     // x bf16; reused as attn out
  bf16_t* wqkvt = (bf16_t*)alloc((size_t)3*F_*E_*2);     // [Wq^T;Wk^T;Wv^T] bf16
  bf16_t* wot   = (bf16_t*)alloc((size_t)F_*E_*2);       // Wo^T bf16 [E][F]
  float2* sc    = (float2*)alloc((size_t)L_*64*sizeof(float2));
  bf16_t* qkv   = (bf16_t*)alloc((size_t)NROW*QS*2);     // fused QKV [4096][6144]
  bf16_t* vt    = (bf16_t*)alloc((size_t)NROW*F_*2);     // V^T [B][H][D][L]
  bf16_t* ob    = xb;                                    // attn output (xb dead by then)

  const float scale2 = 0.08838834764831845f * 1.44269504088896f;  // 1/sqrt(D)*log2(e)

  // 1. fused prep: convert + 4 weight transposes + sincos (one launch)
  k_prep<<<dim3(25088), 256, 0, stream>>>(x, Wq, Wk, Wv, Wo, xb, wqkvt, wot, sc);

  // 2. fused QKV projection + RoPE epilogue: 768 blocks = 3 exact CU rounds
  k_gemm256<bf16_t, 1><<<dim3((QS/256)*(NROW/128)), 512, 0, stream>>>(
      xb, wqkvt, qkv, nullptr, sc, scale2, NROW, QS, E_);

  // 3. V transpose only (RoPE now fused into GEMM epilogue)
  k_vt<<<dim3(8192), 256, 0, stream>>>(qkv, vt);

  // 4. flash attention (flat 512 blocks, XCD bh-chunked)
  k_attn<<<dim3(512), 512, 0, stream>>>(qkv, vt, ob);

  // 5. output projection + bias: 256 blocks = 1 exact CU round
  k_gemm256<float, 2><<<dim3((E_/256)*(NROW/128)), 512, 0, stream>>>(
      ob, wot, out, bo, nullptr, 1.0f, NROW, E_, F_);
}